// Round 20
// baseline (98.758 us; speedup 1.0000x reference)
//
#include <hip/hip_runtime.h>
#include <hip/hip_bf16.h>

// ImageLRU as one GEMM: y[r,:] = W @ x[r,:], W (1024x1024, block-lower-tri)
// built on device. R20 = R19 (compile-fixed): fused-cast GEMM, 3-blocks/CU:
//  - BN 128: per-buf LDS = A-fp32 16KB + W 8KB = 24KB, dbuf 48KB ->
//    3 blocks/CU (12 waves; the R4/R7-proven occupancy that hides drains).
//  - A staged fp32 via global_load_lds, per-lane PRE-SWIZZLED sources
//    (chunk kq^(row&7)), lane-linear dest; frag reads same XOR -> 2-way free.
//  - fp32->bf16 at frag time via __float22bfloat162_rn (v_cvt_pk_bf16_f32);
//    pack extracted with __builtin_memcpy (bit_cast rejected: non-trivial type).
//  - W: kg-major [128n][32k] tiles (R7 layout), gld_lds, conflict-free.
//  - nb-major LPT (L3 keeps X resident; R7-R9 FETCH ~84MB evidence).
//  1-term precision: y = bf16(X)*bf16(W)  (absmax 8192, thr 32768).

namespace {

typedef __attribute__((ext_vector_type(8))) short short8v;
typedef __attribute__((ext_vector_type(4))) float f32x4;
typedef __attribute__((ext_vector_type(4))) unsigned uint4v;

__device__ inline unsigned short f2bf_rne(float f) {
    unsigned u = __builtin_bit_cast(unsigned, f);
    u += 0x7fffu + ((u >> 16) & 1u);
    return (unsigned short)(u >> 16);
}

__device__ inline void gld_lds16(const unsigned short* g, unsigned short* l) {
    __builtin_amdgcn_global_load_lds(
        (const __attribute__((address_space(1))) unsigned int*)g,
        (__attribute__((address_space(3))) unsigned int*)l, 16, 0, 0);
}

__device__ inline unsigned pk2(float a, float b) {
    __hip_bfloat162 h = __float22bfloat162_rn(make_float2(a, b));
    unsigned r;
    __builtin_memcpy(&r, &h, 4);
    return r;
}

// W tile ([128 n][32 k], 4096 ushorts, kg-major): (n,k) at
//   base + ((k>>3)<<10) + (n<<3) + (k&7)         [R7-proven conflict-free]
// A LDS tile: fp32 [128 rows][32 k] row-major; 16B chunk kq stored at
//   slot (row, kq^(row&7)) -> frag reads bank-uniform (2-way, free).

// ---------------- prep: build Wh (bf16) in [128n][32k] tiles ----------------
__global__ __launch_bounds__(256) void build_w_kernel(
    const float* __restrict__ Lre, const float* __restrict__ Lim,
    const float* __restrict__ Bre, const float* __restrict__ Bim,
    const float* __restrict__ Cre, const float* __restrict__ Cim,
    const float* __restrict__ Dm,
    unsigned short* __restrict__ Wh)
{
    const int i = blockIdx.x >> 6, j = blockIdx.x & 63;
    const int t = threadIdx.x, k = t >> 4, l = t & 15;

    const int n_g = i * 16 + k;        // W row (n dim)
    const int k_g = j * 16 + l;        // W col (k dim)
    const size_t widx = (((size_t)((n_g >> 7) * 32 + (k_g >> 5))) << 12)
                      + (((k_g >> 3) & 3) << 10) + ((n_g & 127) << 3) + (k_g & 7);

    if (j > i) { Wh[widx] = 0; return; }

    __shared__ float2 Bs[16][16];
    __shared__ float2 M[16][16];
    Bs[k][l] = make_float2(Bre[t], Bim[t]);
    M[k][l]  = make_float2(k == l ? 1.f : 0.f, 0.f);
    const int delta = i - j;
    __syncthreads();

    #pragma unroll
    for (int d = 0; d < 6; ++d) {
        const int s = 1 << d;
        if (delta & s) {
            const float lr = Lre[k], li = Lim[k];
            const float2 m0 = M[k][l];
            M[k][l] = make_float2(lr * m0.x - li * m0.y, lr * m0.y + li * m0.x);
            __syncthreads();
        } else if (j + (delta & (s - 1)) >= s) {
            float2 acc = make_float2(0.f, 0.f);
            #pragma unroll
            for (int m = 0; m < 16; ++m) {
                const float2 b = Bs[k][m], v = M[m][l];
                acc.x += b.x * v.x - b.y * v.y;
                acc.y += b.x * v.y + b.y * v.x;
            }
            __syncthreads();
            M[k][l] = acc;
            __syncthreads();
        }
    }

    float w = 0.f;
    #pragma unroll
    for (int m = 0; m < 16; ++m) {
        const float2 v = M[m][l];
        w += Cre[k * 16 + m] * v.x - Cim[k * 16 + m] * v.y;
    }
    if (i == j) w += Dm[t];
    Wh[widx] = f2bf_rne(w);
}

// ------ main GEMM: fused cvt, A fp32 swizzle-staged, 128x128, dbuf ----------
__global__ __launch_bounds__(256) void gemm_fused_kernel(
    const float* __restrict__ X,
    const unsigned short* __restrict__ Wh,
    float* __restrict__ Y, int mtiles)
{
    __shared__ alignas(16) float sA[2][4096];            // 2 x 16 KB fp32
    __shared__ alignas(16) unsigned short sB[2][4096];   // 2 x 8 KB bf16

    const int bid = blockIdx.x;
    const int nb = 7 - bid / mtiles;   // heavy N-tiles first (LPT), nb-major
    const int mt = bid % mtiles;
    const int t = threadIdx.x;
    const int wid = t >> 6, lane = t & 63;
    const int wr = wid >> 1, wc = wid & 1;     // 2Mx2N wave grid
    const int l15 = lane & 15, lg = lane >> 4;
    const int nt = (nb + 1) * 4;       // K-tiles of 32

    f32x4 acc[4][4] = {};

    // A frag read offsets (floats): row*32 + ((2lg+e)^(row&7))*4
    int arow[4], as0[4], as1[4];
    #pragma unroll
    for (int mm = 0; mm < 4; ++mm) {
        const int row = wr * 64 + mm * 16 + l15;
        arow[mm] = row << 5;
        as0[mm] = (((2 * lg)     ^ (row & 7)) << 2);
        as1[mm] = (((2 * lg + 1) ^ (row & 7)) << 2);
    }
    // B frag offsets (ushorts) within a W tile
    int bfo[4];
    #pragma unroll
    for (int nn = 0; nn < 4; ++nn)
        bfo[nn] = (lg << 10) + ((wc * 64 + nn * 16 + l15) << 3);

    auto stageT = [&](int b, int tk) {         // 6 gld_lds16 per thread
        float* bA = sA[b];
        unsigned short* bB = sB[b];
        const float* xbase = X + (size_t)mt * 131072 + tk * 32;  // mt*128*1024
        #pragma unroll
        for (int p = 0; p < 4; ++p) {
            const int s = p * 256 + t;
            const int row = s >> 3, kq = s & 7;
            const float* src = xbase + (size_t)row * 1024 + ((kq ^ (row & 7)) << 2);
            gld_lds16((const unsigned short*)src, (unsigned short*)(bA + s * 4));
        }
        const unsigned short* wb = Wh + (((size_t)(nb * 32 + tk)) << 12);
        #pragma unroll
        for (int p = 0; p < 2; ++p) {
            const int e8 = (p * 256 + t) * 8;
            gld_lds16(wb + e8, bB + e8);
        }
    };

    stageT(0, 0);
    __syncthreads();                   // buf0 ready (implicit vmcnt drain)

    for (int tk = 0; tk < nt; ++tk) {
        const int c = tk & 1;
        if (tk + 1 < nt) stageT(c ^ 1, tk + 1);   // DMA in flight across MFMA

        // A fragments: fp32 LDS reads (swizzled, bank-uniform) + cvt_pk
        short8v ah[4];
        #pragma unroll
        for (int mm = 0; mm < 4; ++mm) {
            const f32x4 q0 = *reinterpret_cast<const f32x4*>(sA[c] + arow[mm] + as0[mm]);
            const f32x4 q1 = *reinterpret_cast<const f32x4*>(sA[c] + arow[mm] + as1[mm]);
            uint4v uv;
            uv[0] = pk2(q0[0], q0[1]);
            uv[1] = pk2(q0[2], q0[3]);
            uv[2] = pk2(q1[0], q1[1]);
            uv[3] = pk2(q1[2], q1[3]);
            short8v r;
            __builtin_memcpy(&r, &uv, 16);
            ah[mm] = r;
        }
        short8v bh[4];
        #pragma unroll
        for (int nn = 0; nn < 4; ++nn)
            bh[nn] = *reinterpret_cast<const short8v*>(sB[c] + bfo[nn]);

        __builtin_amdgcn_s_setprio(1);
        #pragma unroll
        for (int mm = 0; mm < 4; ++mm)
            #pragma unroll
            for (int nn = 0; nn < 4; ++nn)
                acc[mm][nn] = __builtin_amdgcn_mfma_f32_16x16x32_bf16(
                    ah[mm], bh[nn], acc[mm][nn], 0, 0, 0);
        __builtin_amdgcn_s_setprio(0);

        __syncthreads();   // readers of buf c done; buf c^1 DMA landed
    }

    // ---- epilogue: C/D layout col=lane&15, row=(lane>>4)*4+q ----
    #pragma unroll
    for (int mm = 0; mm < 4; ++mm) {
        const int grow = mt * 128 + wr * 64 + mm * 16 + lg * 4;
        #pragma unroll
        for (int nn = 0; nn < 4; ++nn) {
            const int gcol = nb * 128 + wc * 64 + nn * 16 + l15;
            #pragma unroll
            for (int q = 0; q < 4; ++q)
                Y[(size_t)(grow + q) * 1024 + gcol] = acc[mm][nn][q];
        }
    }
}

} // namespace

extern "C" void kernel_launch(void* const* d_in, const int* in_sizes, int n_in,
                              void* d_out, int out_size, void* d_ws, size_t ws_size,
                              hipStream_t stream) {
    const float* x   = (const float*)d_in[0];
    const float* Lre = (const float*)d_in[1];
    const float* Lim = (const float*)d_in[2];
    const float* Bre = (const float*)d_in[3];
    const float* Bim = (const float*)d_in[4];
    const float* Cre = (const float*)d_in[5];
    const float* Cim = (const float*)d_in[6];
    const float* Dm  = (const float*)d_in[7];
    float* y = (float*)d_out;

    const int positions = in_sizes[0] / 1024;          // 32768
    const int mtiles = positions / 128;                // 256

    unsigned short* Wh = (unsigned short*)d_ws;        // 2 MB

    build_w_kernel<<<4096, 256, 0, stream>>>(Lre, Lim, Bre, Bim, Cre, Cim, Dm, Wh);
    gemm_fused_kernel<<<mtiles * 8, 256, 0, stream>>>(x, Wh, y, mtiles);
}